// Round 10
// baseline (2404.649 us; speedup 1.0000x reference)
//
#include <hip/hip_runtime.h>

// ---------------------------------------------------------------------------
// NodeNetwork: agg(sum over deg=16) -> concat(3x128) -> MLP(384-256-256-128)
//              -> row L2 normalize.  N=500000 rows.
// R10: persistent two-deep tile pipeline. R9's fused kernel convoyed (all
// blocks stream, then all compute -> HBM duty ~70%, 4.3 TB/s). Now 1024
// persistent blocks grid-stride tiles; next tile's msg loads are issued in
// 8 single-row NT batches woven through the MLP phases of the current tile,
// so the CU never stops streaming. LDS 40KB: XB 24KB (agg|feat|glob,
// self-rolling prefetch) + HB 16KB (h1 -> h2 -> out).
// ---------------------------------------------------------------------------

typedef short short8   __attribute__((ext_vector_type(8)));
typedef short short4_t __attribute__((ext_vector_type(4)));
typedef float f32x4    __attribute__((ext_vector_type(4)));

#define SWZ(row, off) ((off) ^ (((row) & 7) << 4))

__device__ __forceinline__ unsigned short f2bf(float f) {
    unsigned int u = __float_as_uint(f);
    u += 0x7fffu + ((u >> 16) & 1u);   // round-to-nearest-even
    return (unsigned short)(u >> 16);
}

// ---------------------------------------------------------------------------
// Weight prep (unchanged): fp32->bf16, per-lane MFMA B-fragment order:
//   pw[((tn*KS + ks)*64 + lane)*8 + j] = bf16( W[k][n] )
//   n = tn*16 + (lane&15), k = ks*32 + (lane>>4)*8 + j
// ---------------------------------------------------------------------------
__global__ void prep_weights(const float* __restrict__ W1,
                             const float* __restrict__ W2,
                             const float* __restrict__ W3,
                             short* __restrict__ pw1,
                             short* __restrict__ pw2,
                             short* __restrict__ pw3) {
    int idx = blockIdx.x * 256 + threadIdx.x;
    if (idx < 98304) {                       // W1 [384][256]
        int j = idx & 7, l = (idx >> 3) & 63, g = idx >> 9;
        int ks = g % 12, tn = g / 12;
        int n = tn * 16 + (l & 15);
        int k = ks * 32 + ((l >> 4) << 3) + j;
        pw1[idx] = (short)f2bf(W1[k * 256 + n]);
    } else if (idx < 98304 + 65536) {        // W2 [256][256]
        int e = idx - 98304;
        int j = e & 7, l = (e >> 3) & 63, g = e >> 9;
        int ks = g & 7, tn = g >> 3;
        int n = tn * 16 + (l & 15);
        int k = ks * 32 + ((l >> 4) << 3) + j;
        pw2[e] = (short)f2bf(W2[k * 256 + n]);
    } else if (idx < 98304 + 65536 + 32768) { // W3 [256][128]
        int e = idx - 98304 - 65536;
        int j = e & 7, l = (e >> 3) & 63, g = e >> 9;
        int ks = g & 7, tn = g >> 3;
        int n = tn * 16 + (l & 15);
        int k = ks * 32 + ((l >> 4) << 3) + j;
        pw3[e] = (short)f2bf(W3[k * 128 + n]);
    }
}

// ---- prefetch batch macros: one row of next tile, 8x1KB NT loads ----------
#define ISSUE(j) {                                                            \
    const long long rowg_ = rn0 + 8 * w + (j);                                \
    if (rowg_ < n_rows) {                                                     \
        const f32x4* bp_ = (const f32x4*)msg + rowg_ * 512 + lane;            \
        T[0] = __builtin_nontemporal_load(bp_ + 0 * 64);                      \
        T[1] = __builtin_nontemporal_load(bp_ + 1 * 64);                      \
        T[2] = __builtin_nontemporal_load(bp_ + 2 * 64);                      \
        T[3] = __builtin_nontemporal_load(bp_ + 3 * 64);                      \
        T[4] = __builtin_nontemporal_load(bp_ + 4 * 64);                      \
        T[5] = __builtin_nontemporal_load(bp_ + 5 * 64);                      \
        T[6] = __builtin_nontemporal_load(bp_ + 6 * 64);                      \
        T[7] = __builtin_nontemporal_load(bp_ + 7 * 64);                      \
    } else {                                                                  \
        T[0]=zero4; T[1]=zero4; T[2]=zero4; T[3]=zero4;                       \
        T[4]=zero4; T[5]=zero4; T[6]=zero4; T[7]=zero4;                       \
    } }

#define CONSUME(j) {                                                          \
    f32x4 s_ = ((T[0]+T[1])+(T[2]+T[3])) + ((T[4]+T[5])+(T[6]+T[7]));         \
    s_[0] += __shfl_xor(s_[0], 32); s_[1] += __shfl_xor(s_[1], 32);           \
    s_[2] += __shfl_xor(s_[2], 32); s_[3] += __shfl_xor(s_[3], 32);           \
    if (lane < 32) {                                                          \
        short4_t s4_;                                                         \
        s4_[0]=(short)f2bf(s_[0]); s4_[1]=(short)f2bf(s_[1]);                 \
        s4_[2]=(short)f2bf(s_[2]); s4_[3]=(short)f2bf(s_[3]);                 \
        const int rj_ = 8 * w + (j);                                          \
        *(short4_t*)(XB + SWZ(rj_, rj_ * 256 + (lane & 31) * 8)) = s4_;       \
    } }

// ---------------------------------------------------------------------------
// Persistent fused kernel. 256 threads (4 waves), 40KB LDS, grid-stride.
// Invariant at loop top: XB holds x(t) = [agg|feat|glob] fully staged.
// ---------------------------------------------------------------------------
__global__ __launch_bounds__(256, 4) void node_net_pipe(
    const float* __restrict__ msg,
    const float* __restrict__ feat,
    const float* __restrict__ glob,
    const float* __restrict__ b1v,
    const float* __restrict__ b2v,
    const float* __restrict__ b3v,
    const short* __restrict__ pw1,
    const short* __restrict__ pw2,
    const short* __restrict__ pw3,
    float* __restrict__ out,
    int n_rows, int ntiles, int nblk)
{
    __shared__ char lds[40960];
    char* XB = lds;            // 24KB: agg [0:8K], feat [8K:16K], glob [16K:24K]
    char* HB = lds + 24576;    // 16KB: h1 -> h2 -> out (serial reuse)

    const int tid  = threadIdx.x;
    const int lane = tid & 63;
    const int w    = tid >> 6;
    const int lr   = lane & 15;
    const int lk   = lane >> 4;
    const f32x4 zero4 = {0.f, 0.f, 0.f, 0.f};

    // ---- bias prefetch (once) ----
    float bias1[4], bias2[4], bias3[2];
    #pragma unroll
    for (int ci = 0; ci < 4; ++ci) {
        bias1[ci] = b1v[w * 64 + ci * 16 + lr];
        bias2[ci] = b2v[w * 64 + ci * 16 + lr];
    }
    #pragma unroll
    for (int ci = 0; ci < 2; ++ci) bias3[ci] = b3v[w * 32 + ci * 16 + lr];

    long long t = blockIdx.x;

    // ================= prologue: stage x(t) into XB ========================
    {
        const long long r0 = t * 32;
        f32x4 fr[4], gr[4];
        #pragma unroll
        for (int q = 0; q < 4; ++q) {
            int r = (tid >> 5) + q * 8;
            long long row = r0 + r;
            fr[q] = zero4; gr[q] = zero4;
            if (row < n_rows) {
                fr[q] = __builtin_nontemporal_load((const f32x4*)feat + row * 32 + (tid & 31));
                gr[q] = __builtin_nontemporal_load((const f32x4*)glob + row * 32 + (tid & 31));
            }
        }
        // agg: wave w owns rows [8w,8w+8) as 4 pairs, 16x1KB NT loads/pair
        #pragma unroll 1
        for (int pp = 0; pp < 4; ++pp) {
            const int rA = 8 * w + 2 * pp;
            const long long rowA = r0 + rA;
            const f32x4* base = (const f32x4*)msg + rowA * 512;
            f32x4 tA[8], tB[8];
            const bool okA = rowA < n_rows;
            const bool okB = (rowA + 1) < n_rows;
            #pragma unroll
            for (int i = 0; i < 8; ++i)
                tA[i] = okA ? __builtin_nontemporal_load(base + i * 64 + lane) : zero4;
            #pragma unroll
            for (int i = 0; i < 8; ++i)
                tB[i] = okB ? __builtin_nontemporal_load(base + 512 + i * 64 + lane) : zero4;
            f32x4 sA = ((tA[0]+tA[1])+(tA[2]+tA[3])) + ((tA[4]+tA[5])+(tA[6]+tA[7]));
            f32x4 sB = ((tB[0]+tB[1])+(tB[2]+tB[3])) + ((tB[4]+tB[5])+(tB[6]+tB[7]));
            #pragma unroll
            for (int c = 0; c < 4; ++c) {
                sA[c] += __shfl_xor(sA[c], 32);
                sB[c] += __shfl_xor(sB[c], 32);
            }
            f32x4 s = (lane < 32) ? sA : sB;
            short4_t s4;
            s4[0]=(short)f2bf(s[0]); s4[1]=(short)f2bf(s[1]);
            s4[2]=(short)f2bf(s[2]); s4[3]=(short)f2bf(s[3]);
            const int orow = rA + (lane >> 5);
            *(short4_t*)(XB + SWZ(orow, orow * 256 + (lane & 31) * 8)) = s4;
        }
        // stage feat/glob
        #pragma unroll
        for (int q = 0; q < 4; ++q) {
            int r = (tid >> 5) + q * 8;
            short4_t sf, sg;
            sf[0]=(short)f2bf(fr[q][0]); sf[1]=(short)f2bf(fr[q][1]);
            sf[2]=(short)f2bf(fr[q][2]); sf[3]=(short)f2bf(fr[q][3]);
            sg[0]=(short)f2bf(gr[q][0]); sg[1]=(short)f2bf(gr[q][1]);
            sg[2]=(short)f2bf(gr[q][2]); sg[3]=(short)f2bf(gr[q][3]);
            *(short4_t*)(XB + 8192  + SWZ(r, r * 256 + (tid & 31) * 8)) = sf;
            *(short4_t*)(XB + 16384 + SWZ(r, r * 256 + (tid & 31) * 8)) = sg;
        }
    }
    __syncthreads();

    // ================= persistent tile loop ================================
    for (; t < ntiles; t += nblk) {
        const long long r0  = t * 32;
        const long long rn0 = (t + (long long)nblk) * 32;   // prefetch rows
        f32x4 T[8];                                         // batch in flight

        // ---- B1: GEMM1 ks0-3 (agg region) ----
        f32x4 acc1[2][4];
        #pragma unroll
        for (int ri = 0; ri < 2; ++ri)
            #pragma unroll
            for (int ci = 0; ci < 4; ++ci) acc1[ri][ci] = zero4;

        #pragma unroll
        for (int s = 0; s < 4; ++s) {
            short8 a[2], b[4];
            #pragma unroll
            for (int ri = 0; ri < 2; ++ri) {
                int row = ri * 16 + lr;
                a[ri] = *(const short8*)(XB + SWZ(row, row * 256 + s * 64 + lk * 16));
            }
            #pragma unroll
            for (int ci = 0; ci < 4; ++ci)
                b[ci] = *(const short8*)(pw1 + ((((w * 4 + ci) * 12 + s) * 64 + lane) << 3));
            #pragma unroll
            for (int ri = 0; ri < 2; ++ri)
                #pragma unroll
                for (int ci = 0; ci < 4; ++ci)
                    acc1[ri][ci] = __builtin_amdgcn_mfma_f32_16x16x32_bf16(
                        a[ri], b[ci], acc1[ri][ci], 0, 0, 0);
        }
        __syncthreads();                                   // b1 (agg reads done)

        // ---- B2: GEMM1 ks4-11 (feat/glob) + prefetch batches 0-3 ----
        #pragma unroll
        for (int s = 0; s < 8; ++s) {
            if (s == 0) { ISSUE(0) }
            if (s == 2) { CONSUME(0) ISSUE(1) }
            if (s == 4) { CONSUME(1) ISSUE(2) }
            if (s == 6) { CONSUME(2) ISSUE(3) }
            const int ks = 4 + s, p = ks >> 2, ss = ks & 3;
            short8 a[2], b[4];
            #pragma unroll
            for (int ri = 0; ri < 2; ++ri) {
                int row = ri * 16 + lr;
                a[ri] = *(const short8*)(XB + p * 8192 + SWZ(row, row * 256 + ss * 64 + lk * 16));
            }
            #pragma unroll
            for (int ci = 0; ci < 4; ++ci)
                b[ci] = *(const short8*)(pw1 + ((((w * 4 + ci) * 12 + ks) * 64 + lane) << 3));
            #pragma unroll
            for (int ri = 0; ri < 2; ++ri)
                #pragma unroll
                for (int ci = 0; ci < 4; ++ci)
                    acc1[ri][ci] = __builtin_amdgcn_mfma_f32_16x16x32_bf16(
                        a[ri], b[ci], acc1[ri][ci], 0, 0, 0);
        }
        __syncthreads();                                   // b2 (x reads done)

        // ---- epi1: +b1, ReLU -> h1 (HB) ----
        #pragma unroll
        for (int ci = 0; ci < 4; ++ci) {
            int col = w * 64 + ci * 16 + lr;
            #pragma unroll
            for (int ri = 0; ri < 2; ++ri)
                #pragma unroll
                for (int i = 0; i < 4; ++i) {
                    int row = ri * 16 + lk * 4 + i;
                    float v = fmaxf(acc1[ri][ci][i] + bias1[ci], 0.f);
                    *(short*)(HB + SWZ(row, row * 512 + col * 2)) = (short)f2bf(v);
                }
        }
        __syncthreads();                                   // b3

        // ---- G2: h1 @ W2 + prefetch batches 4-7 ----
        f32x4 acc2[2][4];
        #pragma unroll
        for (int ri = 0; ri < 2; ++ri)
            #pragma unroll
            for (int ci = 0; ci < 4; ++ci) acc2[ri][ci] = zero4;

        #pragma unroll
        for (int s = 0; s < 8; ++s) {
            if (s == 0) { CONSUME(3) ISSUE(4) }
            if (s == 2) { CONSUME(4) ISSUE(5) }
            if (s == 4) { CONSUME(5) ISSUE(6) }
            if (s == 6) { CONSUME(6) ISSUE(7) }
            short8 a[2], b[4];
            #pragma unroll
            for (int ri = 0; ri < 2; ++ri) {
                int row = ri * 16 + lr;
                a[ri] = *(const short8*)(HB + SWZ(row, row * 512 + s * 64 + lk * 16));
            }
            #pragma unroll
            for (int ci = 0; ci < 4; ++ci)
                b[ci] = *(const short8*)(pw2 + ((((w * 4 + ci) * 8 + s) * 64 + lane) << 3));
            #pragma unroll
            for (int ri = 0; ri < 2; ++ri)
                #pragma unroll
                for (int ci = 0; ci < 4; ++ci)
                    acc2[ri][ci] = __builtin_amdgcn_mfma_f32_16x16x32_bf16(
                        a[ri], b[ci], acc2[ri][ci], 0, 0, 0);
        }
        __syncthreads();                                   // b4 (h1 reads done)

        // ---- epi2: +b2, ReLU -> h2 (HB, h1 dead) ----
        #pragma unroll
        for (int ci = 0; ci < 4; ++ci) {
            int col = w * 64 + ci * 16 + lr;
            #pragma unroll
            for (int ri = 0; ri < 2; ++ri)
                #pragma unroll
                for (int i = 0; i < 4; ++i) {
                    int row = ri * 16 + lk * 4 + i;
                    float v = fmaxf(acc2[ri][ci][i] + bias2[ci], 0.f);
                    *(short*)(HB + SWZ(row, row * 512 + col * 2)) = (short)f2bf(v);
                }
        }
        __syncthreads();                                   // b5

        // ---- G3: h2 @ W3 + consume batch7 + fr/gr prefetch ----
        f32x4 fr[4], gr[4];
        f32x4 acc3[2][2];
        #pragma unroll
        for (int ri = 0; ri < 2; ++ri)
            #pragma unroll
            for (int ci = 0; ci < 2; ++ci) acc3[ri][ci] = zero4;

        #pragma unroll
        for (int s = 0; s < 8; ++s) {
            if (s == 0) {
                CONSUME(7)
                #pragma unroll
                for (int q = 0; q < 4; ++q) {
                    int r = (tid >> 5) + q * 8;
                    long long row = rn0 + r;
                    fr[q] = zero4; gr[q] = zero4;
                    if (row < n_rows) {
                        fr[q] = __builtin_nontemporal_load((const f32x4*)feat + row * 32 + (tid & 31));
                        gr[q] = __builtin_nontemporal_load((const f32x4*)glob + row * 32 + (tid & 31));
                    }
                }
            }
            short8 a[2], b[2];
            #pragma unroll
            for (int ri = 0; ri < 2; ++ri) {
                int row = ri * 16 + lr;
                a[ri] = *(const short8*)(HB + SWZ(row, row * 512 + s * 64 + lk * 16));
            }
            #pragma unroll
            for (int ci = 0; ci < 2; ++ci)
                b[ci] = *(const short8*)(pw3 + ((((w * 2 + ci) * 8 + s) * 64 + lane) << 3));
            #pragma unroll
            for (int ri = 0; ri < 2; ++ri)
                #pragma unroll
                for (int ci = 0; ci < 2; ++ci)
                    acc3[ri][ci] = __builtin_amdgcn_mfma_f32_16x16x32_bf16(
                        a[ri], b[ci], acc3[ri][ci], 0, 0, 0);
        }
        // stage fr/gr for next tile (XB feat/glob regions free since b2)
        #pragma unroll
        for (int q = 0; q < 4; ++q) {
            int r = (tid >> 5) + q * 8;
            short4_t sf, sg;
            sf[0]=(short)f2bf(fr[q][0]); sf[1]=(short)f2bf(fr[q][1]);
            sf[2]=(short)f2bf(fr[q][2]); sf[3]=(short)f2bf(fr[q][3]);
            sg[0]=(short)f2bf(gr[q][0]); sg[1]=(short)f2bf(gr[q][1]);
            sg[2]=(short)f2bf(gr[q][2]); sg[3]=(short)f2bf(gr[q][3]);
            *(short4_t*)(XB + 8192  + SWZ(r, r * 256 + (tid & 31) * 8)) = sf;
            *(short4_t*)(XB + 16384 + SWZ(r, r * 256 + (tid & 31) * 8)) = sg;
        }
        __syncthreads();                                   // b6 (h2 reads done)

        // ---- epi3: +b3 -> out f32 (HB, h2 dead) ----
        #pragma unroll
        for (int ci = 0; ci < 2; ++ci) {
            int col = w * 32 + ci * 16 + lr;
            #pragma unroll
            for (int ri = 0; ri < 2; ++ri)
                #pragma unroll
                for (int i = 0; i < 4; ++i) {
                    int row = ri * 16 + lk * 4 + i;
                    float v = acc3[ri][ci][i] + bias3[ci];
                    *(float*)(HB + SWZ(row, row * 512 + col * 4)) = v;
                }
        }
        __syncthreads();                                   // b7

        // ---- norm + NT store ----
        #pragma unroll
        for (int pass = 0; pass < 4; ++pass) {
            const int r  = (tid >> 5) + pass * 8;
            const int fl = tid & 31;
            f32x4 v = *(const f32x4*)(HB + SWZ(r, r * 512 + fl * 16));
            float ss = v[0]*v[0] + v[1]*v[1] + v[2]*v[2] + v[3]*v[3];
            ss += __shfl_xor(ss, 1, 32);
            ss += __shfl_xor(ss, 2, 32);
            ss += __shfl_xor(ss, 4, 32);
            ss += __shfl_xor(ss, 8, 32);
            ss += __shfl_xor(ss, 16, 32);
            float inv = 1.f / (sqrtf(ss) + 1e-8f);
            long long row = r0 + r;
            if (row < n_rows) {
                f32x4 o = v * inv;
                __builtin_nontemporal_store(o, (f32x4*)out + row * 32 + fl);
            }
        }
        // no barrier needed: next B1 only READS XB agg (written pre-b6);
        // first HB write of next iter (epi1) is gated by b2/b3 of next iter,
        // by which every wave has finished this norm phase.
    }
}

// ---------------------------------------------------------------------------
extern "C" void kernel_launch(void* const* d_in, const int* in_sizes, int n_in,
                              void* d_out, int out_size, void* d_ws, size_t ws_size,
                              hipStream_t stream) {
    const float* msg  = (const float*)d_in[0];
    const float* feat = (const float*)d_in[1];
    const float* glob = (const float*)d_in[2];
    const float* W1   = (const float*)d_in[3];
    const float* b1   = (const float*)d_in[4];
    const float* W2   = (const float*)d_in[5];
    const float* b2   = (const float*)d_in[6];
    const float* W3   = (const float*)d_in[7];
    const float* b3   = (const float*)d_in[8];
    float* out = (float*)d_out;

    const int n_rows = in_sizes[1] / 128;   // features is [N,128]
    const int ntiles = (n_rows + 31) / 32;
    const int nblk   = ntiles < 1024 ? ntiles : 1024;  // 4 blocks/CU resident

    short* pw1 = (short*)d_ws;              // 98304 bf16
    short* pw2 = pw1 + 98304;               // 65536 bf16
    short* pw3 = pw2 + 65536;               // 32768 bf16

    hipLaunchKernelGGL(prep_weights, dim3(768), dim3(256), 0, stream,
                       W1, W2, W3, pw1, pw2, pw3);

    hipLaunchKernelGGL(node_net_pipe, dim3(nblk), dim3(256), 0, stream,
                       msg, feat, glob, b1, b2, b3, pw1, pw2, pw3, out,
                       n_rows, ntiles, nblk);
}

// Round 11
// 1474.615 us; speedup vs baseline: 1.6307x; 1.6307x over previous
//
#include <hip/hip_runtime.h>

// ---------------------------------------------------------------------------
// NodeNetwork: agg(sum over deg=16) -> concat(3x128) -> MLP(384-256-256-128)
//              -> row L2 normalize.  N=500000 rows.
// R11: BARRIER-FREE fused kernel. R10 proved cross-barrier prefetch is
// impossible at HIP level (compiler emits s_waitcnt vmcnt(0) before every
// s_barrier). So: one wave per 16 rows, zero __syncthreads. MLP computed
// TRANSPOSED (h^T = W^T * x^T): A-frags = packed W^T (identical pw packing),
// B-frags = x^T (col=node). Layer-to-layer handoff via wave-private LDS
// bounce (DS ops within a wave are in-order -> no barrier). Streaming NT
// loads pipeline freely across the whole MLP; 16 waves/CU hide the rest.
// ---------------------------------------------------------------------------

typedef short short8   __attribute__((ext_vector_type(8)));
typedef short short4_t __attribute__((ext_vector_type(4)));
typedef float f32x4    __attribute__((ext_vector_type(4)));

#define SWZ(row, off) ((off) ^ (((row) & 7) << 4))

__device__ __forceinline__ unsigned short f2bf(float f) {
    unsigned int u = __float_as_uint(f);
    u += 0x7fffu + ((u >> 16) & 1u);   // round-to-nearest-even
    return (unsigned short)(u >> 16);
}

// ---------------------------------------------------------------------------
// Weight prep (unchanged packing — it already matches W^T-as-A-frag layout):
//   pw[((m*KS + ks)*64 + l)*8 + j] = bf16( W[k][h] )
//   h = m*16 + (l&15), k = ks*32 + (l>>4)*8 + j
// A-frag for h^T = W^T x^T: lane l holds row h = l&15 (within M-frag m),
// k = (l>>4)*8+j  ->  exactly this packing.
// ---------------------------------------------------------------------------
__global__ void prep_weights(const float* __restrict__ W1,
                             const float* __restrict__ W2,
                             const float* __restrict__ W3,
                             short* __restrict__ pw1,
                             short* __restrict__ pw2,
                             short* __restrict__ pw3) {
    int idx = blockIdx.x * 256 + threadIdx.x;
    if (idx < 98304) {                       // W1 [384][256]
        int j = idx & 7, l = (idx >> 3) & 63, g = idx >> 9;
        int ks = g % 12, tn = g / 12;
        int n = tn * 16 + (l & 15);
        int k = ks * 32 + ((l >> 4) << 3) + j;
        pw1[idx] = (short)f2bf(W1[k * 256 + n]);
    } else if (idx < 98304 + 65536) {        // W2 [256][256]
        int e = idx - 98304;
        int j = e & 7, l = (e >> 3) & 63, g = e >> 9;
        int ks = g & 7, tn = g >> 3;
        int n = tn * 16 + (l & 15);
        int k = ks * 32 + ((l >> 4) << 3) + j;
        pw2[e] = (short)f2bf(W2[k * 256 + n]);
    } else if (idx < 98304 + 65536 + 32768) { // W3 [256][128]
        int e = idx - 98304 - 65536;
        int j = e & 7, l = (e >> 3) & 63, g = e >> 9;
        int ks = g & 7, tn = g >> 3;
        int n = tn * 16 + (l & 15);
        int k = ks * 32 + ((l >> 4) << 3) + j;
        pw3[e] = (short)f2bf(W3[k * 128 + n]);
    }
}

// ---------------------------------------------------------------------------
// One wave (64 threads) per 16 rows. LDS 8KB, wave-private, no barriers:
//   bytes [0:4K]  : agg bf16 [16 node][128 k]   (stride 256, XOR-swizzled)
//   bytes [0:8K]  : later h bf16 [16 node][256] (stride 512; agg dead by then)
// All global streams NT (msg/feat/glob loads, out stores) -> weights stay
// L2-resident (R8-proven).
// ---------------------------------------------------------------------------
__global__ __launch_bounds__(64, 4) void node_wave(
    const float* __restrict__ msg,
    const float* __restrict__ feat,
    const float* __restrict__ glob,
    const float* __restrict__ b1v,
    const float* __restrict__ b2v,
    const float* __restrict__ b3v,
    const short* __restrict__ pw1,
    const short* __restrict__ pw2,
    const short* __restrict__ pw3,
    float* __restrict__ out,
    int n_rows)
{
    __shared__ char lds[8192];

    const int l    = threadIdx.x;      // 0..63, one wave
    const int node = l & 15;
    const int lk   = l >> 4;
    const long long r0 = (long long)blockIdx.x * 16;
    const f32x4 zero4 = {0.f, 0.f, 0.f, 0.f};

    // ================= Phase A: aggregate 16 rows of msg ===================
    // chunk = 2 rows; 16 x 1KB wave-contiguous NT loads; shfl_xor(32) merge.
    #pragma unroll 1
    for (int c = 0; c < 8; ++c) {
        const int rA = 2 * c;
        const long long gA = r0 + rA;
        const f32x4* base = (const f32x4*)msg + gA * 512;
        const bool okA = gA < n_rows;
        const bool okB = (gA + 1) < n_rows;
        f32x4 tA[8], tB[8];
        #pragma unroll
        for (int i = 0; i < 8; ++i)
            tA[i] = okA ? __builtin_nontemporal_load(base + i * 64 + l) : zero4;
        #pragma unroll
        for (int i = 0; i < 8; ++i)
            tB[i] = okB ? __builtin_nontemporal_load(base + 512 + i * 64 + l) : zero4;
        f32x4 sA = ((tA[0]+tA[1])+(tA[2]+tA[3])) + ((tA[4]+tA[5])+(tA[6]+tA[7]));
        f32x4 sB = ((tB[0]+tB[1])+(tB[2]+tB[3])) + ((tB[4]+tB[5])+(tB[6]+tB[7]));
        #pragma unroll
        for (int q = 0; q < 4; ++q) {
            sA[q] += __shfl_xor(sA[q], 32);
            sB[q] += __shfl_xor(sB[q], 32);
        }
        f32x4 s = (l < 32) ? sA : sB;
        short4_t s4;
        s4[0] = (short)f2bf(s[0]); s4[1] = (short)f2bf(s[1]);
        s4[2] = (short)f2bf(s[2]); s4[3] = (short)f2bf(s[3]);
        const int orow = rA + (l >> 5);
        *(short4_t*)(lds + SWZ(orow, orow * 256 + (l & 31) * 8)) = s4;
    }

    // ================= GEMM1': h1^T = W1^T * x^T (12 ks, 16 m-frags) =======
    f32x4 acc1[16];
    #pragma unroll
    for (int m = 0; m < 16; ++m) acc1[m] = zero4;

    #pragma unroll
    for (int ks = 0; ks < 12; ++ks) {
        short8 bx;
        if (ks < 4) {
            // agg from LDS: [node][k], k = ks*32 + lk*8 + j
            bx = *(const short8*)(lds + SWZ(node, node * 256 + ks * 64 + lk * 16));
        } else {
            // feat (ks 4..7) / glob (ks 8..11) straight from global, NT
            const float* src = (ks < 8) ? feat : glob;
            const int kk = (ks < 8) ? (ks - 4) : (ks - 8);
            const long long row = r0 + node;
            f32x4 ra = zero4, rb = zero4;
            if (row < n_rows) {
                const f32x4* p = (const f32x4*)src + row * 32 + kk * 8 + lk * 2;
                ra = __builtin_nontemporal_load(p);
                rb = __builtin_nontemporal_load(p + 1);
            }
            bx[0] = (short)f2bf(ra[0]); bx[1] = (short)f2bf(ra[1]);
            bx[2] = (short)f2bf(ra[2]); bx[3] = (short)f2bf(ra[3]);
            bx[4] = (short)f2bf(rb[0]); bx[5] = (short)f2bf(rb[1]);
            bx[6] = (short)f2bf(rb[2]); bx[7] = (short)f2bf(rb[3]);
        }
        #pragma unroll
        for (int m = 0; m < 16; ++m) {
            short8 wa = *(const short8*)(pw1 + (((m * 12 + ks) * 64 + l) << 3));
            acc1[m] = __builtin_amdgcn_mfma_f32_16x16x32_bf16(wa, bx, acc1[m], 0, 0, 0);
        }
    }

    // ---- epi1: +b1, ReLU -> h1 bf16 [node][256] in LDS (agg is dead) ------
    // lane l holds h-units (16m + lk*4 + i) for node l&15.
    #pragma unroll
    for (int m = 0; m < 16; ++m) {
        f32x4 b4 = *(const f32x4*)(b1v + m * 16 + lk * 4);
        short4_t h4;
        #pragma unroll
        for (int i = 0; i < 4; ++i)
            h4[i] = (short)f2bf(fmaxf(acc1[m][i] + b4[i], 0.f));
        *(short4_t*)(lds + SWZ(node, node * 512 + m * 32 + lk * 8)) = h4;
    }

    // ================= GEMM2': h2^T = W2^T * h1^T (8 ks, 16 m) =============
    f32x4 acc2[16];
    #pragma unroll
    for (int m = 0; m < 16; ++m) acc2[m] = zero4;

    #pragma unroll
    for (int ks = 0; ks < 8; ++ks) {
        short8 bx = *(const short8*)(lds + SWZ(node, node * 512 + ks * 64 + lk * 16));
        #pragma unroll
        for (int m = 0; m < 16; ++m) {
            short8 wa = *(const short8*)(pw2 + (((m * 8 + ks) * 64 + l) << 3));
            acc2[m] = __builtin_amdgcn_mfma_f32_16x16x32_bf16(wa, bx, acc2[m], 0, 0, 0);
        }
    }

    // ---- epi2: +b2, ReLU -> h2 bf16 [node][256] in LDS (h1 dead) ----------
    #pragma unroll
    for (int m = 0; m < 16; ++m) {
        f32x4 b4 = *(const f32x4*)(b2v + m * 16 + lk * 4);
        short4_t h4;
        #pragma unroll
        for (int i = 0; i < 4; ++i)
            h4[i] = (short)f2bf(fmaxf(acc2[m][i] + b4[i], 0.f));
        *(short4_t*)(lds + SWZ(node, node * 512 + m * 32 + lk * 8)) = h4;
    }

    // ================= GEMM3': out^T = W3^T * h2^T (8 ks, 8 m) =============
    f32x4 acc3[8];
    #pragma unroll
    for (int m = 0; m < 8; ++m) acc3[m] = zero4;

    #pragma unroll
    for (int ks = 0; ks < 8; ++ks) {
        short8 bx = *(const short8*)(lds + SWZ(node, node * 512 + ks * 64 + lk * 16));
        #pragma unroll
        for (int m = 0; m < 8; ++m) {
            short8 wa = *(const short8*)(pw3 + (((m * 8 + ks) * 64 + l) << 3));
            acc3[m] = __builtin_amdgcn_mfma_f32_16x16x32_bf16(wa, bx, acc3[m], 0, 0, 0);
        }
    }

    // ---- epi3 + row-L2 norm + NT store ------------------------------------
    // lane l holds out-dims (16m + lk*4 + i) for node l&15 (32 values).
    float ss = 0.f;
    #pragma unroll
    for (int m = 0; m < 8; ++m) {
        f32x4 b4 = *(const f32x4*)(b3v + m * 16 + lk * 4);
        #pragma unroll
        for (int i = 0; i < 4; ++i) {
            acc3[m][i] += b4[i];
            ss += acc3[m][i] * acc3[m][i];
        }
    }
    // reduce across the 4 lanes (lk=0..3) sharing this node
    ss += __shfl_xor(ss, 16);
    ss += __shfl_xor(ss, 32);
    const float inv = 1.f / (sqrtf(ss) + 1e-8f);

    const long long row = r0 + node;
    if (row < n_rows) {
        #pragma unroll
        for (int m = 0; m < 8; ++m) {
            f32x4 o = acc3[m] * inv;
            __builtin_nontemporal_store(o, (f32x4*)out + row * 32 + m * 4 + lk);
        }
    }
}

// ---------------------------------------------------------------------------
extern "C" void kernel_launch(void* const* d_in, const int* in_sizes, int n_in,
                              void* d_out, int out_size, void* d_ws, size_t ws_size,
                              hipStream_t stream) {
    const float* msg  = (const float*)d_in[0];
    const float* feat = (const float*)d_in[1];
    const float* glob = (const float*)d_in[2];
    const float* W1   = (const float*)d_in[3];
    const float* b1   = (const float*)d_in[4];
    const float* W2   = (const float*)d_in[5];
    const float* b2   = (const float*)d_in[6];
    const float* W3   = (const float*)d_in[7];
    const float* b3   = (const float*)d_in[8];
    float* out = (float*)d_out;

    const int n_rows = in_sizes[1] / 128;   // features is [N,128]

    short* pw1 = (short*)d_ws;              // 98304 bf16
    short* pw2 = pw1 + 98304;               // 65536 bf16
    short* pw3 = pw2 + 65536;               // 32768 bf16

    hipLaunchKernelGGL(prep_weights, dim3(768), dim3(256), 0, stream,
                       W1, W2, W3, pw1, pw2, pw3);

    const int nblocks = (n_rows + 15) / 16;  // one 64-thread wave per 16 rows
    hipLaunchKernelGGL(node_wave, dim3(nblocks), dim3(64), 0, stream,
                       msg, feat, glob, b1, b2, b3, pw1, pw2, pw3, out, n_rows);
}

// Round 12
// 1298.565 us; speedup vs baseline: 1.8518x; 1.1356x over previous
//
#include <hip/hip_runtime.h>

// ---------------------------------------------------------------------------
// NodeNetwork: agg(sum over deg=16) -> concat(3x128) -> MLP(384-256-256-128)
//              -> row L2 normalize.  N=500000 rows.
// R12: slim R9 (best=1080us) for occupancy. Peak VGPR cut to fit
// launch_bounds(256,5) -> 5 blocks/CU (20 waves, was 16):
//   - Phase A: 8 single-row chunks (tA[8]=32 VGPR, was tA+tB=64)
//   - glob loaded at its staging point (only fr[4]=16 VGPR live in Phase A)
//   - guardless hot path (500000%32==0 -> full tiles; 'full' flag hoisted)
// All else byte-identical to R9: NT streams (weights stay L2-resident, R8),
// fused agg+MLP (R9), 6 syncs, same GEMM/epilogue structure, same prep.
// ---------------------------------------------------------------------------

typedef short short8   __attribute__((ext_vector_type(8)));
typedef short short4_t __attribute__((ext_vector_type(4)));
typedef float f32x4    __attribute__((ext_vector_type(4)));

#define SWZ(row, off) ((off) ^ (((row) & 7) << 4))

__device__ __forceinline__ unsigned short f2bf(float f) {
    unsigned int u = __float_as_uint(f);
    u += 0x7fffu + ((u >> 16) & 1u);   // round-to-nearest-even
    return (unsigned short)(u >> 16);
}

// ---------------------------------------------------------------------------
// Weight prep (unchanged): fp32->bf16, per-lane MFMA B-fragment order:
//   pw[((tn*KS + ks)*64 + lane)*8 + j] = bf16( W[k][n] )
//   n = tn*16 + (lane&15), k = ks*32 + (lane>>4)*8 + j
// ---------------------------------------------------------------------------
__global__ void prep_weights(const float* __restrict__ W1,
                             const float* __restrict__ W2,
                             const float* __restrict__ W3,
                             short* __restrict__ pw1,
                             short* __restrict__ pw2,
                             short* __restrict__ pw3) {
    int idx = blockIdx.x * 256 + threadIdx.x;
    if (idx < 98304) {                       // W1 [384][256]
        int j = idx & 7, l = (idx >> 3) & 63, g = idx >> 9;
        int ks = g % 12, tn = g / 12;
        int n = tn * 16 + (l & 15);
        int k = ks * 32 + ((l >> 4) << 3) + j;
        pw1[idx] = (short)f2bf(W1[k * 256 + n]);
    } else if (idx < 98304 + 65536) {        // W2 [256][256]
        int e = idx - 98304;
        int j = e & 7, l = (e >> 3) & 63, g = e >> 9;
        int ks = g & 7, tn = g >> 3;
        int n = tn * 16 + (l & 15);
        int k = ks * 32 + ((l >> 4) << 3) + j;
        pw2[e] = (short)f2bf(W2[k * 256 + n]);
    } else if (idx < 98304 + 65536 + 32768) { // W3 [256][128]
        int e = idx - 98304 - 65536;
        int j = e & 7, l = (e >> 3) & 63, g = e >> 9;
        int ks = g & 7, tn = g >> 3;
        int n = tn * 16 + (l & 15);
        int k = ks * 32 + ((l >> 4) << 3) + j;
        pw3[e] = (short)f2bf(W3[k * 128 + n]);
    }
}

// ---------------------------------------------------------------------------
// Fused kernel: 32 rows/block, 256 threads (4 waves), 32KB LDS, 5 blocks/CU.
// ---------------------------------------------------------------------------
__global__ __launch_bounds__(256, 5) void node_net_fused(
    const float* __restrict__ msg,
    const float* __restrict__ feat,
    const float* __restrict__ glob,
    const float* __restrict__ b1v,
    const float* __restrict__ b2v,
    const float* __restrict__ b3v,
    const short* __restrict__ pw1,
    const short* __restrict__ pw2,
    const short* __restrict__ pw3,
    float* __restrict__ out,
    int n_rows)
{
    __shared__ char lds[32768];
    char* regA = lds;            // 16KB
    char* regB = lds + 16384;    // 16KB

    const int tid  = threadIdx.x;
    const int lane = tid & 63;
    const int w    = tid >> 6;
    const int lr   = lane & 15;
    const int lk   = lane >> 4;
    const long long r0 = (long long)blockIdx.x * 32;
    const bool full = (r0 + 32) <= (long long)n_rows;  // always true @ N=500k

    const f32x4 zero4 = {0.f, 0.f, 0.f, 0.f};

    // ---- feat NT loads at entry (16 VGPR live through Phase A) ----
    f32x4 fr[4];
    #pragma unroll
    for (int q = 0; q < 4; ++q) {
        int r = (tid >> 5) + q * 8;
        long long row = r0 + r;
        fr[q] = zero4;
        if (full || row < n_rows)
            fr[q] = __builtin_nontemporal_load((const f32x4*)feat + row * 32 + (tid & 31));
    }

    // ---- Phase A: msg aggregation -> regB[0:8K] ----
    // Wave w owns rows [8w,8w+8); chunk = 1 row = 8 x 1KB wave-contig NT loads.
    // Lane l sums f4=l&31 over d in {(l>>5)+2i}; shfl_xor(32) merges parity.
    #pragma unroll 1
    for (int c = 0; c < 8; ++c) {
        const int rr = 8 * w + c;
        const long long grow = r0 + rr;
        const f32x4* base = (const f32x4*)msg + grow * 512;
        f32x4 t[8];
        if (full || grow < n_rows) {
            #pragma unroll
            for (int i = 0; i < 8; ++i)
                t[i] = __builtin_nontemporal_load(base + i * 64 + lane);
        } else {
            #pragma unroll
            for (int i = 0; i < 8; ++i) t[i] = zero4;
        }
        f32x4 s = ((t[0] + t[1]) + (t[2] + t[3])) + ((t[4] + t[5]) + (t[6] + t[7]));
        #pragma unroll
        for (int q = 0; q < 4; ++q) s[q] += __shfl_xor(s[q], 32);
        if (lane < 32) {
            short4_t s4;
            s4[0] = (short)f2bf(s[0]); s4[1] = (short)f2bf(s[1]);
            s4[2] = (short)f2bf(s[2]); s4[3] = (short)f2bf(s[3]);
            *(short4_t*)(regB + SWZ(rr, rr * 256 + lane * 8)) = s4;
        }
    }
    __syncthreads();                                   // sync1

    // ---- stage feat regs -> regA[0:8K] (consumed after sync2) ----
    #pragma unroll
    for (int q = 0; q < 4; ++q) {
        int r = (tid >> 5) + q * 8;
        short4_t s4;
        s4[0] = (short)f2bf(fr[q][0]); s4[1] = (short)f2bf(fr[q][1]);
        s4[2] = (short)f2bf(fr[q][2]); s4[3] = (short)f2bf(fr[q][3]);
        *(short4_t*)(regA + SWZ(r, r * 256 + (tid & 31) * 8)) = s4;
    }

    f32x4 acc1[2][4];
    #pragma unroll
    for (int ri = 0; ri < 2; ++ri)
        #pragma unroll
        for (int ci = 0; ci < 4; ++ci) acc1[ri][ci] = zero4;

    // ---- GEMM1 part 0 (agg), ks = 0..3, reads regB[0:8K] ----
    #pragma unroll
    for (int s = 0; s < 4; ++s) {
        short8 a[2], b[4];
        #pragma unroll
        for (int ri = 0; ri < 2; ++ri) {
            int row = ri * 16 + lr;
            a[ri] = *(const short8*)(regB + SWZ(row, row * 256 + s * 64 + lk * 16));
        }
        #pragma unroll
        for (int ci = 0; ci < 4; ++ci) {
            int tn = w * 4 + ci;
            b[ci] = *(const short8*)(pw1 + (((tn * 12 + s) * 64 + lane) << 3));
        }
        #pragma unroll
        for (int ri = 0; ri < 2; ++ri)
            #pragma unroll
            for (int ci = 0; ci < 4; ++ci)
                acc1[ri][ci] = __builtin_amdgcn_mfma_f32_16x16x32_bf16(
                    a[ri], b[ci], acc1[ri][ci], 0, 0, 0);
    }
    __syncthreads();                                   // sync2

    // ---- load glob NT here + stage -> regB[8K:16K] (consumed after sync3) ----
    #pragma unroll
    for (int q = 0; q < 4; ++q) {
        int r = (tid >> 5) + q * 8;
        long long row = r0 + r;
        f32x4 g = zero4;
        if (full || row < n_rows)
            g = __builtin_nontemporal_load((const f32x4*)glob + row * 32 + (tid & 31));
        short4_t s4;
        s4[0] = (short)f2bf(g[0]); s4[1] = (short)f2bf(g[1]);
        s4[2] = (short)f2bf(g[2]); s4[3] = (short)f2bf(g[3]);
        *(short4_t*)(regB + 8192 + SWZ(r, r * 256 + (tid & 31) * 8)) = s4;
    }

    // ---- GEMM1 part 1 (feat), ks = 4..7, reads regA[0:8K] ----
    #pragma unroll
    for (int s = 0; s < 4; ++s) {
        short8 a[2], b[4];
        #pragma unroll
        for (int ri = 0; ri < 2; ++ri) {
            int row = ri * 16 + lr;
            a[ri] = *(const short8*)(regA + SWZ(row, row * 256 + s * 64 + lk * 16));
        }
        #pragma unroll
        for (int ci = 0; ci < 4; ++ci) {
            int tn = w * 4 + ci;
            b[ci] = *(const short8*)(pw1 + (((tn * 12 + 4 + s) * 64 + lane) << 3));
        }
        #pragma unroll
        for (int ri = 0; ri < 2; ++ri)
            #pragma unroll
            for (int ci = 0; ci < 4; ++ci)
                acc1[ri][ci] = __builtin_amdgcn_mfma_f32_16x16x32_bf16(
                    a[ri], b[ci], acc1[ri][ci], 0, 0, 0);
    }
    __syncthreads();                                   // sync3

    // ---- GEMM1 part 2 (glob), ks = 8..11, reads regB[8K:16K] ----
    #pragma unroll
    for (int s = 0; s < 4; ++s) {
        short8 a[2], b[4];
        #pragma unroll
        for (int ri = 0; ri < 2; ++ri) {
            int row = ri * 16 + lr;
            a[ri] = *(const short8*)(regB + 8192 + SWZ(row, row * 256 + s * 64 + lk * 16));
        }
        #pragma unroll
        for (int ci = 0; ci < 4; ++ci) {
            int tn = w * 4 + ci;
            b[ci] = *(const short8*)(pw1 + (((tn * 12 + 8 + s) * 64 + lane) << 3));
        }
        #pragma unroll
        for (int ri = 0; ri < 2; ++ri)
            #pragma unroll
            for (int ci = 0; ci < 4; ++ci)
                acc1[ri][ci] = __builtin_amdgcn_mfma_f32_16x16x32_bf16(
                    a[ri], b[ci], acc1[ri][ci], 0, 0, 0);
    }

    // ---- epilogue 1: +b1, ReLU, bf16 -> h1 in regA ----
    #pragma unroll
    for (int ci = 0; ci < 4; ++ci) {
        int col = w * 64 + ci * 16 + lr;
        float bias = b1v[col];
        #pragma unroll
        for (int ri = 0; ri < 2; ++ri)
            #pragma unroll
            for (int i = 0; i < 4; ++i) {
                int row = ri * 16 + lk * 4 + i;
                float v = fmaxf(acc1[ri][ci][i] + bias, 0.f);
                *(short*)(regA + SWZ(row, row * 512 + col * 2)) = (short)f2bf(v);
            }
    }
    __syncthreads();                                   // sync4

    // ---- GEMM2: h1 @ W2 (reads regA) ----
    f32x4 acc2[2][4];
    #pragma unroll
    for (int ri = 0; ri < 2; ++ri)
        #pragma unroll
        for (int ci = 0; ci < 4; ++ci) acc2[ri][ci] = zero4;

    #pragma unroll
    for (int s = 0; s < 8; ++s) {
        short8 a[2], b[4];
        #pragma unroll
        for (int ri = 0; ri < 2; ++ri) {
            int row = ri * 16 + lr;
            a[ri] = *(const short8*)(regA + SWZ(row, row * 512 + s * 64 + lk * 16));
        }
        #pragma unroll
        for (int ci = 0; ci < 4; ++ci) {
            int tn = w * 4 + ci;
            b[ci] = *(const short8*)(pw2 + (((tn * 8 + s) * 64 + lane) << 3));
        }
        #pragma unroll
        for (int ri = 0; ri < 2; ++ri)
            #pragma unroll
            for (int ci = 0; ci < 4; ++ci)
                acc2[ri][ci] = __builtin_amdgcn_mfma_f32_16x16x32_bf16(
                    a[ri], b[ci], acc2[ri][ci], 0, 0, 0);
    }

    // ---- epilogue 2: +b2, ReLU, bf16 -> h2 in regB ----
    #pragma unroll
    for (int ci = 0; ci < 4; ++ci) {
        int col = w * 64 + ci * 16 + lr;
        float bias = b2v[col];
        #pragma unroll
        for (int ri = 0; ri < 2; ++ri)
            #pragma unroll
            for (int i = 0; i < 4; ++i) {
                int row = ri * 16 + lk * 4 + i;
                float v = fmaxf(acc2[ri][ci][i] + bias, 0.f);
                *(short*)(regB + SWZ(row, row * 512 + col * 2)) = (short)f2bf(v);
            }
    }
    __syncthreads();                                   // sync5

    // ---- GEMM3: h2 @ W3 (reads regB) ----
    f32x4 acc3[2][2];
    #pragma unroll
    for (int ri = 0; ri < 2; ++ri)
        #pragma unroll
        for (int ci = 0; ci < 2; ++ci) acc3[ri][ci] = zero4;

    #pragma unroll
    for (int s = 0; s < 8; ++s) {
        short8 a[2], b[2];
        #pragma unroll
        for (int ri = 0; ri < 2; ++ri) {
            int row = ri * 16 + lr;
            a[ri] = *(const short8*)(regB + SWZ(row, row * 512 + s * 64 + lk * 16));
        }
        #pragma unroll
        for (int ci = 0; ci < 2; ++ci) {
            int tn = w * 2 + ci;
            b[ci] = *(const short8*)(pw3 + (((tn * 8 + s) * 64 + lane) << 3));
        }
        #pragma unroll
        for (int ri = 0; ri < 2; ++ri)
            #pragma unroll
            for (int ci = 0; ci < 2; ++ci)
                acc3[ri][ci] = __builtin_amdgcn_mfma_f32_16x16x32_bf16(
                    a[ri], b[ci], acc3[ri][ci], 0, 0, 0);
    }

    // ---- epilogue 3: +b3, f32 -> out tile in regA ----
    #pragma unroll
    for (int ci = 0; ci < 2; ++ci) {
        int col = w * 32 + ci * 16 + lr;
        float bias = b3v[col];
        #pragma unroll
        for (int ri = 0; ri < 2; ++ri)
            #pragma unroll
            for (int i = 0; i < 4; ++i) {
                int row = ri * 16 + lk * 4 + i;
                float v = acc3[ri][ci][i] + bias;
                *(float*)(regA + SWZ(row, row * 512 + col * 4)) = v;
            }
    }
    __syncthreads();                                   // sync6

    // ---- row-wise L2 normalize + coalesced NT store ----
    #pragma unroll
    for (int pass = 0; pass < 4; ++pass) {
        const int r  = (tid >> 5) + pass * 8;
        const int fl = tid & 31;
        f32x4 v = *(const f32x4*)(regA + SWZ(r, r * 512 + fl * 16));
        float ss = v[0]*v[0] + v[1]*v[1] + v[2]*v[2] + v[3]*v[3];
        ss += __shfl_xor(ss, 1, 32);
        ss += __shfl_xor(ss, 2, 32);
        ss += __shfl_xor(ss, 4, 32);
        ss += __shfl_xor(ss, 8, 32);
        ss += __shfl_xor(ss, 16, 32);
        float inv = 1.f / (sqrtf(ss) + 1e-8f);
        long long row = r0 + r;
        if (row < n_rows) {
            f32x4 o = v * inv;
            __builtin_nontemporal_store(o, (f32x4*)out + row * 32 + fl);
        }
    }
}

// ---------------------------------------------------------------------------
extern "C" void kernel_launch(void* const* d_in, const int* in_sizes, int n_in,
                              void* d_out, int out_size, void* d_ws, size_t ws_size,
                              hipStream_t stream) {
    const float* msg  = (const float*)d_in[0];
    const float* feat = (const float*)d_in[1];
    const float* glob = (const float*)d_in[2];
    const float* W1   = (const float*)d_in[3];
    const float* b1   = (const float*)d_in[4];
    const float* W2   = (const float*)d_in[5];
    const float* b2   = (const float*)d_in[6];
    const float* W3   = (const float*)d_in[7];
    const float* b3   = (const float*)d_in[8];
    float* out = (float*)d_out;

    const int n_rows = in_sizes[1] / 128;   // features is [N,128]

    short* pw1 = (short*)d_ws;              // 98304 bf16
    short* pw2 = pw1 + 98304;               // 65536 bf16
    short* pw3 = pw2 + 65536;               // 32768 bf16

    hipLaunchKernelGGL(prep_weights, dim3(768), dim3(256), 0, stream,
                       W1, W2, W3, pw1, pw2, pw3);

    const int nblocks = (n_rows + 31) / 32;
    hipLaunchKernelGGL(node_net_fused, dim3(nblocks), dim3(256), 0, stream,
                       msg, feat, glob, b1, b2, b3, pw1, pw2, pw3, out, n_rows);
}

// Round 13
// 1118.518 us; speedup vs baseline: 2.1499x; 1.1610x over previous
//
#include <hip/hip_runtime.h>

// ---------------------------------------------------------------------------
// NodeNetwork: agg(sum over deg=16) -> concat(3x128) -> MLP(384-256-256-128)
//              -> row L2 normalize.  N=500000 rows.
// R13: R9 (best, 1080us) + ENTRY STAGGER. Fused blocks convoy (all resident
// blocks stream together, then MLP together -> HBM duty ~70%). A per-block
// pseudo-random delay of {0..3} x ~0.8us (hash of blockIdx; hashed because
// same-CU indices differ by ~256 under XCD round-robin) de-phases co-resident
// blocks so one streams while another runs its MLP. Kernel body is
// byte-identical to R9 otherwise (single-variable A/B).
// ---------------------------------------------------------------------------

typedef short short8   __attribute__((ext_vector_type(8)));
typedef short short4_t __attribute__((ext_vector_type(4)));
typedef float f32x4    __attribute__((ext_vector_type(4)));

#define SWZ(row, off) ((off) ^ (((row) & 7) << 4))

__device__ __forceinline__ unsigned short f2bf(float f) {
    unsigned int u = __float_as_uint(f);
    u += 0x7fffu + ((u >> 16) & 1u);   // round-to-nearest-even
    return (unsigned short)(u >> 16);
}

// ---------------------------------------------------------------------------
// Weight prep (unchanged): fp32->bf16, per-lane MFMA B-fragment order:
//   pw[((tn*KS + ks)*64 + lane)*8 + j] = bf16( W[k][n] )
//   n = tn*16 + (lane&15), k = ks*32 + (lane>>4)*8 + j
// ---------------------------------------------------------------------------
__global__ void prep_weights(const float* __restrict__ W1,
                             const float* __restrict__ W2,
                             const float* __restrict__ W3,
                             short* __restrict__ pw1,
                             short* __restrict__ pw2,
                             short* __restrict__ pw3) {
    int idx = blockIdx.x * 256 + threadIdx.x;
    if (idx < 98304) {                       // W1 [384][256]
        int j = idx & 7, l = (idx >> 3) & 63, g = idx >> 9;
        int ks = g % 12, tn = g / 12;
        int n = tn * 16 + (l & 15);
        int k = ks * 32 + ((l >> 4) << 3) + j;
        pw1[idx] = (short)f2bf(W1[k * 256 + n]);
    } else if (idx < 98304 + 65536) {        // W2 [256][256]
        int e = idx - 98304;
        int j = e & 7, l = (e >> 3) & 63, g = e >> 9;
        int ks = g & 7, tn = g >> 3;
        int n = tn * 16 + (l & 15);
        int k = ks * 32 + ((l >> 4) << 3) + j;
        pw2[e] = (short)f2bf(W2[k * 256 + n]);
    } else if (idx < 98304 + 65536 + 32768) { // W3 [256][128]
        int e = idx - 98304 - 65536;
        int j = e & 7, l = (e >> 3) & 63, g = e >> 9;
        int ks = g & 7, tn = g >> 3;
        int n = tn * 16 + (l & 15);
        int k = ks * 32 + ((l >> 4) << 3) + j;
        pw3[e] = (short)f2bf(W3[k * 128 + n]);
    }
}

// ---------------------------------------------------------------------------
// Fused kernel: 32 rows/block, 256 threads (4 waves), 32KB LDS, 4 blocks/CU.
// Structure identical to R9; stagger spin added at entry.
// ---------------------------------------------------------------------------
__global__ __launch_bounds__(256, 4) void node_net_fused(
    const float* __restrict__ msg,
    const float* __restrict__ feat,
    const float* __restrict__ glob,
    const float* __restrict__ b1v,
    const float* __restrict__ b2v,
    const float* __restrict__ b3v,
    const short* __restrict__ pw1,
    const short* __restrict__ pw2,
    const short* __restrict__ pw3,
    float* __restrict__ out,
    int n_rows)
{
    __shared__ char lds[32768];
    char* regA = lds;            // 16KB
    char* regB = lds + 16384;    // 16KB

    // ---- entry stagger: de-phase co-resident blocks (hash, not &3) ----
    {
        const unsigned key = ((unsigned)blockIdx.x * 2654435761u) >> 30;  // 0..3
        const int spin = (int)key * 500;           // ~0.8us per unit
        for (int i = 0; i < spin; ++i)
            asm volatile("s_nop 0" ::: "memory");
    }

    const int tid  = threadIdx.x;
    const int lane = tid & 63;
    const int w    = tid >> 6;
    const int lr   = lane & 15;
    const int lk   = lane >> 4;
    const long long r0 = (long long)blockIdx.x * 32;

    const f32x4 zero4 = {0.f, 0.f, 0.f, 0.f};

    // ---- issue feat/glob NT loads first (consumed after sync1/sync2) ----
    f32x4 fr[4], gr[4];
    #pragma unroll
    for (int q = 0; q < 4; ++q) {
        int r = (tid >> 5) + q * 8;
        long long row = r0 + r;
        fr[q] = zero4; gr[q] = zero4;
        if (row < n_rows) {
            fr[q] = __builtin_nontemporal_load((const f32x4*)feat + row * 32 + (tid & 31));
            gr[q] = __builtin_nontemporal_load((const f32x4*)glob + row * 32 + (tid & 31));
        }
    }

    // ---- Phase A: msg aggregation -> regB[0:8K] ----
    // Wave w owns rows [8w, 8w+8) as 4 pairs; per pair 16 x 1KB NT loads.
    #pragma unroll 1
    for (int pp = 0; pp < 4; ++pp) {
        const int rA = 8 * w + 2 * pp;          // tile-local row (pair base)
        const long long rowA = r0 + rA;
        const f32x4* base = (const f32x4*)msg + rowA * 512;  // 512 f32x4/row
        f32x4 tA[8], tB[8];
        const bool okA = rowA < n_rows;
        const bool okB = (rowA + 1) < n_rows;
        #pragma unroll
        for (int i = 0; i < 8; ++i)
            tA[i] = okA ? __builtin_nontemporal_load(base + i * 64 + lane) : zero4;
        #pragma unroll
        for (int i = 0; i < 8; ++i)
            tB[i] = okB ? __builtin_nontemporal_load(base + 512 + i * 64 + lane) : zero4;
        f32x4 sA = ((tA[0]+tA[1])+(tA[2]+tA[3])) + ((tA[4]+tA[5])+(tA[6]+tA[7]));
        f32x4 sB = ((tB[0]+tB[1])+(tB[2]+tB[3])) + ((tB[4]+tB[5])+(tB[6]+tB[7]));
        #pragma unroll
        for (int c = 0; c < 4; ++c) {
            sA[c] += __shfl_xor(sA[c], 32);
            sB[c] += __shfl_xor(sB[c], 32);
        }
        f32x4 s = (lane < 32) ? sA : sB;
        short4_t s4;
        s4[0] = (short)f2bf(s[0]); s4[1] = (short)f2bf(s[1]);
        s4[2] = (short)f2bf(s[2]); s4[3] = (short)f2bf(s[3]);
        const int orow = rA + (lane >> 5);
        *(short4_t*)(regB + SWZ(orow, orow * 256 + (lane & 31) * 8)) = s4;
    }
    __syncthreads();                                   // sync1

    // ---- stage feat regs -> regA[0:8K] (consumed after sync2) ----
    #pragma unroll
    for (int q = 0; q < 4; ++q) {
        int r = (tid >> 5) + q * 8;
        short4_t s4;
        s4[0] = (short)f2bf(fr[q][0]); s4[1] = (short)f2bf(fr[q][1]);
        s4[2] = (short)f2bf(fr[q][2]); s4[3] = (short)f2bf(fr[q][3]);
        *(short4_t*)(regA + SWZ(r, r * 256 + (tid & 31) * 8)) = s4;
    }

    f32x4 acc1[2][4];
    #pragma unroll
    for (int ri = 0; ri < 2; ++ri)
        #pragma unroll
        for (int ci = 0; ci < 4; ++ci) acc1[ri][ci] = zero4;

    // ---- GEMM1 part 0 (agg), ks = 0..3, reads regB[0:8K] ----
    #pragma unroll
    for (int s = 0; s < 4; ++s) {
        short8 a[2], b[4];
        #pragma unroll
        for (int ri = 0; ri < 2; ++ri) {
            int row = ri * 16 + lr;
            a[ri] = *(const short8*)(regB + SWZ(row, row * 256 + s * 64 + lk * 16));
        }
        #pragma unroll
        for (int ci = 0; ci < 4; ++ci) {
            int tn = w * 4 + ci;
            b[ci] = *(const short8*)(pw1 + (((tn * 12 + s) * 64 + lane) << 3));
        }
        #pragma unroll
        for (int ri = 0; ri < 2; ++ri)
            #pragma unroll
            for (int ci = 0; ci < 4; ++ci)
                acc1[ri][ci] = __builtin_amdgcn_mfma_f32_16x16x32_bf16(
                    a[ri], b[ci], acc1[ri][ci], 0, 0, 0);
    }
    __syncthreads();                                   // sync2

    // ---- stage glob regs -> regB[8K:16K] (consumed after sync3) ----
    #pragma unroll
    for (int q = 0; q < 4; ++q) {
        int r = (tid >> 5) + q * 8;
        short4_t s4;
        s4[0] = (short)f2bf(gr[q][0]); s4[1] = (short)f2bf(gr[q][1]);
        s4[2] = (short)f2bf(gr[q][2]); s4[3] = (short)f2bf(gr[q][3]);
        *(short4_t*)(regB + 8192 + SWZ(r, r * 256 + (tid & 31) * 8)) = s4;
    }

    // ---- GEMM1 part 1 (feat), ks = 4..7, reads regA[0:8K] ----
    #pragma unroll
    for (int s = 0; s < 4; ++s) {
        short8 a[2], b[4];
        #pragma unroll
        for (int ri = 0; ri < 2; ++ri) {
            int row = ri * 16 + lr;
            a[ri] = *(const short8*)(regA + SWZ(row, row * 256 + s * 64 + lk * 16));
        }
        #pragma unroll
        for (int ci = 0; ci < 4; ++ci) {
            int tn = w * 4 + ci;
            b[ci] = *(const short8*)(pw1 + (((tn * 12 + 4 + s) * 64 + lane) << 3));
        }
        #pragma unroll
        for (int ri = 0; ri < 2; ++ri)
            #pragma unroll
            for (int ci = 0; ci < 4; ++ci)
                acc1[ri][ci] = __builtin_amdgcn_mfma_f32_16x16x32_bf16(
                    a[ri], b[ci], acc1[ri][ci], 0, 0, 0);
    }
    __syncthreads();                                   // sync3

    // ---- GEMM1 part 2 (glob), ks = 8..11, reads regB[8K:16K] ----
    #pragma unroll
    for (int s = 0; s < 4; ++s) {
        short8 a[2], b[4];
        #pragma unroll
        for (int ri = 0; ri < 2; ++ri) {
            int row = ri * 16 + lr;
            a[ri] = *(const short8*)(regB + 8192 + SWZ(row, row * 256 + s * 64 + lk * 16));
        }
        #pragma unroll
        for (int ci = 0; ci < 4; ++ci) {
            int tn = w * 4 + ci;
            b[ci] = *(const short8*)(pw1 + (((tn * 12 + 8 + s) * 64 + lane) << 3));
        }
        #pragma unroll
        for (int ri = 0; ri < 2; ++ri)
            #pragma unroll
            for (int ci = 0; ci < 4; ++ci)
                acc1[ri][ci] = __builtin_amdgcn_mfma_f32_16x16x32_bf16(
                    a[ri], b[ci], acc1[ri][ci], 0, 0, 0);
    }

    // ---- epilogue 1: +b1, ReLU, bf16 -> h1 in regA ----
    #pragma unroll
    for (int ci = 0; ci < 4; ++ci) {
        int col = w * 64 + ci * 16 + lr;
        float bias = b1v[col];
        #pragma unroll
        for (int ri = 0; ri < 2; ++ri)
            #pragma unroll
            for (int i = 0; i < 4; ++i) {
                int row = ri * 16 + lk * 4 + i;
                float v = fmaxf(acc1[ri][ci][i] + bias, 0.f);
                *(short*)(regA + SWZ(row, row * 512 + col * 2)) = (short)f2bf(v);
            }
    }
    __syncthreads();                                   // sync4

    // ---- GEMM2: h1 @ W2 (reads regA) ----
    f32x4 acc2[2][4];
    #pragma unroll
    for (int ri = 0; ri < 2; ++ri)
        #pragma unroll
        for (int ci = 0; ci < 4; ++ci) acc2[ri][ci] = zero4;

    #pragma unroll
    for (int s = 0; s < 8; ++s) {
        short8 a[2], b[4];
        #pragma unroll
        for (int ri = 0; ri < 2; ++ri) {
            int row = ri * 16 + lr;
            a[ri] = *(const short8*)(regA + SWZ(row, row * 512 + s * 64 + lk * 16));
        }
        #pragma unroll
        for (int ci = 0; ci < 4; ++ci) {
            int tn = w * 4 + ci;
            b[ci] = *(const short8*)(pw2 + (((tn * 8 + s) * 64 + lane) << 3));
        }
        #pragma unroll
        for (int ri = 0; ri < 2; ++ri)
            #pragma unroll
            for (int ci = 0; ci < 4; ++ci)
                acc2[ri][ci] = __builtin_amdgcn_mfma_f32_16x16x32_bf16(
                    a[ri], b[ci], acc2[ri][ci], 0, 0, 0);
    }

    // ---- epilogue 2: +b2, ReLU, bf16 -> h2 in regB ----
    #pragma unroll
    for (int ci = 0; ci < 4; ++ci) {
        int col = w * 64 + ci * 16 + lr;
        float bias = b2v[col];
        #pragma unroll
        for (int ri = 0; ri < 2; ++ri)
            #pragma unroll
            for (int i = 0; i < 4; ++i) {
                int row = ri * 16 + lk * 4 + i;
                float v = fmaxf(acc2[ri][ci][i] + bias, 0.f);
                *(short*)(regB + SWZ(row, row * 512 + col * 2)) = (short)f2bf(v);
            }
    }
    __syncthreads();                                   // sync5

    // ---- GEMM3: h2 @ W3 (reads regB) ----
    f32x4 acc3[2][2];
    #pragma unroll
    for (int ri = 0; ri < 2; ++ri)
        #pragma unroll
        for (int ci = 0; ci < 2; ++ci) acc3[ri][ci] = zero4;

    #pragma unroll
    for (int s = 0; s < 8; ++s) {
        short8 a[2], b[2];
        #pragma unroll
        for (int ri = 0; ri < 2; ++ri) {
            int row = ri * 16 + lr;
            a[ri] = *(const short8*)(regB + SWZ(row, row * 512 + s * 64 + lk * 16));
        }
        #pragma unroll
        for (int ci = 0; ci < 2; ++ci) {
            int tn = w * 2 + ci;
            b[ci] = *(const short8*)(pw3 + (((tn * 8 + s) * 64 + lane) << 3));
        }
        #pragma unroll
        for (int ri = 0; ri < 2; ++ri)
            #pragma unroll
            for (int ci = 0; ci < 2; ++ci)
                acc3[ri][ci] = __builtin_amdgcn_mfma_f32_16x16x32_bf16(
                    a[ri], b[ci], acc3[ri][ci], 0, 0, 0);
    }

    // ---- epilogue 3: +b3, f32 -> out tile in regA ----
    #pragma unroll
    for (int ci = 0; ci < 2; ++ci) {
        int col = w * 32 + ci * 16 + lr;
        float bias = b3v[col];
        #pragma unroll
        for (int ri = 0; ri < 2; ++ri)
            #pragma unroll
            for (int i = 0; i < 4; ++i) {
                int row = ri * 16 + lk * 4 + i;
                float v = acc3[ri][ci][i] + bias;
                *(float*)(regA + SWZ(row, row * 512 + col * 4)) = v;
            }
    }
    __syncthreads();                                   // sync6

    // ---- row-wise L2 normalize + coalesced NT store ----
    #pragma unroll
    for (int pass = 0; pass < 4; ++pass) {
        const int r  = (tid >> 5) + pass * 8;
        const int fl = tid & 31;
        f32x4 v = *(const f32x4*)(regA + SWZ(r, r * 512 + fl * 16));
        float ss = v[0]*v[0] + v[1]*v[1] + v[2]*v[2] + v[3]*v[3];
        ss += __shfl_xor(ss, 1, 32);
        ss += __shfl_xor(ss, 2, 32);
        ss += __shfl_xor(ss, 4, 32);
        ss += __shfl_xor(ss, 8, 32);
        ss += __shfl_xor(ss, 16, 32);
        float inv = 1.f / (sqrtf(ss) + 1e-8f);
        long long row = r0 + r;
        if (row < n_rows) {
            f32x4 o = v * inv;
            __builtin_nontemporal_store(o, (f32x4*)out + row * 32 + fl);
        }
    }
}

// ---------------------------------------------------------------------------
extern "C" void kernel_launch(void* const* d_in, const int* in_sizes, int n_in,
                              void* d_out, int out_size, void* d_ws, size_t ws_size,
                              hipStream_t stream) {
    const float* msg  = (const float*)d_in[0];
    const float* feat = (const float*)d_in[1];
    const float* glob = (const float*)d_in[2];
    const float* W1   = (const float*)d_in[3];
    const float* b1   = (const float*)d_in[4];
    const float* W2   = (const float*)d_in[5];
    const float* b2   = (const float*)d_in[6];
    const float* W3   = (const float*)d_in[7];
    const float* b3   = (const float*)d_in[8];
    float* out = (float*)d_out;

    const int n_rows = in_sizes[1] / 128;   // features is [N,128]

    short* pw1 = (short*)d_ws;              // 98304 bf16
    short* pw2 = pw1 + 98304;               // 65536 bf16
    short* pw3 = pw2 + 65536;               // 32768 bf16

    hipLaunchKernelGGL(prep_weights, dim3(768), dim3(256), 0, stream,
                       W1, W2, W3, pw1, pw2, pw3);

    const int nblocks = (n_rows + 31) / 32;
    hipLaunchKernelGGL(node_net_fused, dim3(nblocks), dim3(256), 0, stream,
                       msg, feat, glob, b1, b2, b3, pw1, pw2, pw3, out, n_rows);
}